// Round 1
// baseline (596.820 us; speedup 1.0000x reference)
//
#include <hip/hip_runtime.h>

#define VOC 49408
#define TD 512
#define DM 768
#define NROWS 1024
#define NCOLG 386   // VOC / 128
#define NTILES 772  // VOC / 64
#define NSPLIT 16

typedef __attribute__((ext_vector_type(8))) short bf16x8;
typedef __attribute__((ext_vector_type(4))) float f32x4;

__device__ __forceinline__ unsigned short f2bf(float f) {
  unsigned int u = __float_as_uint(f);
  u += 0x7fffu + ((u >> 16) & 1u);   // RNE
  return (unsigned short)(u >> 16);
}

__device__ __forceinline__ void gload16(const void* g, const void* l) {
  __builtin_amdgcn_global_load_lds(
      (const __attribute__((address_space(1))) void*)g,
      (__attribute__((address_space(3))) void*)l, 16, 0, 0);
}

// ---------------------------------------------------------------- K1: proj + normalize
// grid 256, block 256. 4 rows per block.
__global__ __launch_bounds__(256) void k_proj(const float* __restrict__ kw,
                                              const float* __restrict__ Wp,
                                              const float* __restrict__ bp,
                                              unsigned short* __restrict__ kwn) {
  __shared__ float row_lds[4 * DM];
  __shared__ float rsum[4][4];
  __shared__ float rinv_s[4];
  const int t = threadIdx.x;
  const int rb = blockIdx.x * 4;
  for (int i = 0; i < 12; ++i) {
    int idx = i * 256 + t;
    row_lds[idx] = kw[(size_t)rb * DM + idx];
  }
  __syncthreads();
  float acc[4][2] = {};
  for (int m = 0; m < DM; ++m) {
    float w0 = Wp[m * TD + t];
    float w1 = Wp[m * TD + t + 256];
#pragma unroll
    for (int r = 0; r < 4; ++r) {
      float kv = row_lds[r * DM + m];
      acc[r][0] = fmaf(kv, w0, acc[r][0]);
      acc[r][1] = fmaf(kv, w1, acc[r][1]);
    }
  }
  const float b0 = bp[t], b1 = bp[t + 256];
  float p[4];
#pragma unroll
  for (int r = 0; r < 4; ++r) {
    acc[r][0] += b0;
    acc[r][1] += b1;
    p[r] = acc[r][0] * acc[r][0] + acc[r][1] * acc[r][1];
  }
#pragma unroll
  for (int off = 32; off; off >>= 1) {
#pragma unroll
    for (int r = 0; r < 4; ++r) p[r] += __shfl_down(p[r], off);
  }
  const int lane = t & 63, wv = t >> 6;
  if (lane == 0) {
#pragma unroll
    for (int r = 0; r < 4; ++r) rsum[r][wv] = p[r];
  }
  __syncthreads();
  if (t < 4) {
    float s = rsum[t][0] + rsum[t][1] + rsum[t][2] + rsum[t][3];
    rinv_s[t] = 1.0f / fmaxf(sqrtf(s), 1e-8f);
  }
  __syncthreads();
#pragma unroll
  for (int r = 0; r < 4; ++r) {
    float ri = rinv_s[r];
    kwn[(size_t)(rb + r) * TD + t] = f2bf(acc[r][0] * ri);
    kwn[(size_t)(rb + r) * TD + t + 256] = f2bf(acc[r][1] * ri);
  }
}

// ---------------------------------------------------------------- K2: emb normalize
// grid VOC, block 64 (one wave per row).
__global__ __launch_bounds__(64) void k_embnorm(const float* __restrict__ We,
                                                unsigned short* __restrict__ embn,
                                                float* __restrict__ normv) {
  const int v = blockIdx.x;
  const int t = threadIdx.x;
  const float* rowp = We + (size_t)v * TD;
  float4 a = *(const float4*)(rowp + t * 8);
  float4 b = *(const float4*)(rowp + t * 8 + 4);
  float ss = a.x * a.x + a.y * a.y + a.z * a.z + a.w * a.w +
             b.x * b.x + b.y * b.y + b.z * b.z + b.w * b.w;
#pragma unroll
  for (int off = 1; off < 64; off <<= 1) ss += __shfl_xor(ss, off);
  const float nrm = sqrtf(ss);
  const float ri = 1.0f / fmaxf(nrm, 1e-8f);
  bf16x8 o;
  o[0] = (short)f2bf(a.x * ri); o[1] = (short)f2bf(a.y * ri);
  o[2] = (short)f2bf(a.z * ri); o[3] = (short)f2bf(a.w * ri);
  o[4] = (short)f2bf(b.x * ri); o[5] = (short)f2bf(b.y * ri);
  o[6] = (short)f2bf(b.z * ri); o[7] = (short)f2bf(b.w * ri);
  *(bf16x8*)(embn + (size_t)v * TD + t * 8) = o;
  if (t == 0) normv[v] = nrm;
}

// ---------------------------------------------------------------- K2b: transpose embn -> embnT
// grid (772, 8), block 256. 64x64 tiles via LDS.
__global__ __launch_bounds__(256) void k_transpose(const unsigned short* __restrict__ embn,
                                                   unsigned short* __restrict__ embnT) {
  __shared__ unsigned short tile[64 * 72];
  const int t = threadIdx.x;
  const int v0 = blockIdx.x * 64, d0 = blockIdx.y * 64;
#pragma unroll
  for (int p = 0; p < 2; ++p) {
    int vl = p * 32 + (t >> 3), ch = t & 7;
    *(bf16x8*)&tile[vl * 72 + ch * 8] =
        *(const bf16x8*)(embn + (size_t)(v0 + vl) * TD + d0 + ch * 8);
  }
  __syncthreads();
#pragma unroll
  for (int p = 0; p < 2; ++p) {
    int dl = p * 32 + (t >> 3), vch = t & 7;
    bf16x8 o;
#pragma unroll
    for (int i = 0; i < 8; ++i) o[i] = (short)tile[(vch * 8 + i) * 72 + dl];
    *(bf16x8*)(embnT + (size_t)(d0 + dl) * VOC + v0 + vch * 8) = o;
  }
}

// ---------------------------------------------------------------- K3: cos GEMM + sumexp partials
// grid (386, 8), block 256 (4 waves, 2x2 of 64x64). 128x128 tile, BK=64.
__global__ __launch_bounds__(256) void k_cos(const unsigned short* __restrict__ kwn,
                                             const unsigned short* __restrict__ embn,
                                             float* __restrict__ cosd,
                                             float* __restrict__ partial) {
  __shared__ unsigned short As[128 * 64];
  __shared__ unsigned short Bs[128 * 64];
  __shared__ float rs[2][128];
  const int t = threadIdx.x;
  const int colg = blockIdx.x, rowg = blockIdx.y;
  const int lane = t & 63, w = t >> 6;
  const int wm = w >> 1, wn = w & 1;
  const int g = lane >> 4, l15 = lane & 15;

  f32x4 acc[4][4];
#pragma unroll
  for (int mi = 0; mi < 4; ++mi)
#pragma unroll
    for (int ni = 0; ni < 4; ++ni)
#pragma unroll
      for (int j = 0; j < 4; ++j) acc[mi][ni][j] = 0.0f;

  const unsigned short* Ab = kwn + (size_t)rowg * 128 * TD + (size_t)(t >> 3) * TD + (t & 7) * 8;
  const unsigned short* Bb = embn + (size_t)colg * 128 * TD + (size_t)(t >> 3) * TD + (t & 7) * 8;

  for (int kt = 0; kt < 8; ++kt) {
#pragma unroll
    for (int i = 0; i < 4; ++i) {
      gload16(Ab + (size_t)(i * 32) * TD + kt * 64, (const void*)(As + i * 2048 + w * 512));
      gload16(Bb + (size_t)(i * 32) * TD + kt * 64, (const void*)(Bs + i * 2048 + w * 512));
    }
    __syncthreads();
#pragma unroll
    for (int ks = 0; ks < 2; ++ks) {
      bf16x8 a[4], b[4];
#pragma unroll
      for (int mi = 0; mi < 4; ++mi)
        a[mi] = *(const bf16x8*)&As[(wm * 64 + mi * 16 + l15) * 64 + ks * 32 + g * 8];
#pragma unroll
      for (int ni = 0; ni < 4; ++ni)
        b[ni] = *(const bf16x8*)&Bs[(wn * 64 + ni * 16 + l15) * 64 + ks * 32 + g * 8];
#pragma unroll
      for (int mi = 0; mi < 4; ++mi)
#pragma unroll
        for (int ni = 0; ni < 4; ++ni)
          acc[mi][ni] =
              __builtin_amdgcn_mfma_f32_16x16x32_bf16(a[mi], b[ni], acc[mi][ni], 0, 0, 0);
    }
    __syncthreads();
  }

  // epilogue: write cos, per-row sum of exp
  const size_t rowbase = (size_t)rowg * 128 + wm * 64;
  const int colbase = colg * 128 + wn * 64;
#pragma unroll
  for (int mi = 0; mi < 4; ++mi) {
    float es[4] = {0.f, 0.f, 0.f, 0.f};
#pragma unroll
    for (int ni = 0; ni < 4; ++ni) {
#pragma unroll
      for (int j = 0; j < 4; ++j) {
        float c = acc[mi][ni][j];
        cosd[(rowbase + mi * 16 + g * 4 + j) * VOC + colbase + ni * 16 + l15] = c;
        es[j] += __expf(c);
      }
    }
#pragma unroll
    for (int j = 0; j < 4; ++j) {
      float e = es[j];
      e += __shfl_xor(e, 1);
      e += __shfl_xor(e, 2);
      e += __shfl_xor(e, 4);
      e += __shfl_xor(e, 8);
      if (l15 == 0) rs[wn][wm * 64 + mi * 16 + g * 4 + j] = e;
    }
  }
  __syncthreads();
  if (t < 128) {
    float srow = rs[0][t] + rs[1][t];
    partial[(size_t)colg * 1024 + rowg * 128 + t] = srow;
  }
}

// ---------------------------------------------------------------- K3b: denom reduce
// grid 4, block 256.
__global__ __launch_bounds__(256) void k_denom(const float* __restrict__ partial,
                                               float* __restrict__ rdenom) {
  const int row = blockIdx.x * 256 + threadIdx.x;
  float s = 0.f;
  for (int gI = 0; gI < NCOLG; ++gI) s += partial[(size_t)gI * 1024 + row];
  rdenom[row] = 1.0f / s;
}

// ---------------------------------------------------------------- K4: prob + PV GEMM (split-K)
// grid (16, 32), block 256. Each block: 32 rows x 512 d, ~48 vocab tiles of 64.
__global__ __launch_bounds__(256, 2) void k_pv(const float* __restrict__ cosd,
                                               const unsigned short* __restrict__ embnT,
                                               const float* __restrict__ normv,
                                               const float* __restrict__ rdenom,
                                               float* __restrict__ prob,
                                               float* __restrict__ kpart) {
  __shared__ unsigned short apn[32 * 72];
  __shared__ float stage[32 * 257];
  const int t = threadIdx.x;
  const int s = blockIdx.x;
  const int rg = blockIdx.y;
  const int lane = t & 63, w = t >> 6;
  const int g = lane >> 4, l15 = lane & 15;
  const int tbase = NTILES / NSPLIT;          // 48
  const int rem = NTILES % NSPLIT;            // 4
  const int t0 = s * tbase + (s < rem ? s : rem);
  const int t1 = t0 + tbase + (s < rem ? 1 : 0);

  const int srow = t >> 3;
  const int sch = t & 7;
  const size_t growO = (size_t)(rg * 32 + srow) * VOC;
  const float rdv = rdenom[rg * 32 + srow];

  f32x4 acc[8][2];
#pragma unroll
  for (int df = 0; df < 8; ++df)
#pragma unroll
    for (int rf = 0; rf < 2; ++rf)
#pragma unroll
      for (int j = 0; j < 4; ++j) acc[df][rf][j] = 0.0f;

  for (int kt = t0; kt < t1; ++kt) {
    const int v0 = kt * 64;
    const float* cp = cosd + growO + v0 + sch * 8;
    const float* nvp = normv + v0 + sch * 8;
    float4 c0 = *(const float4*)(cp);
    float4 c1 = *(const float4*)(cp + 4);
    float4 n0 = *(const float4*)(nvp);
    float4 n1 = *(const float4*)(nvp + 4);
    float4 p0, p1;
    p0.x = __expf(c0.x) * rdv; p0.y = __expf(c0.y) * rdv;
    p0.z = __expf(c0.z) * rdv; p0.w = __expf(c0.w) * rdv;
    p1.x = __expf(c1.x) * rdv; p1.y = __expf(c1.y) * rdv;
    p1.z = __expf(c1.z) * rdv; p1.w = __expf(c1.w) * rdv;
    *(float4*)(prob + growO + v0 + sch * 8) = p0;
    *(float4*)(prob + growO + v0 + sch * 8 + 4) = p1;
    bf16x8 pv;
    pv[0] = (short)f2bf(p0.x * n0.x);
    pv[1] = (short)f2bf(p0.y * n0.y);
    pv[2] = (short)f2bf(p0.z * n0.z);
    pv[3] = (short)f2bf(p0.w * n0.w);
    pv[4] = (short)f2bf(p1.x * n1.x);
    pv[5] = (short)f2bf(p1.y * n1.y);
    pv[6] = (short)f2bf(p1.z * n1.z);
    pv[7] = (short)f2bf(p1.w * n1.w);
    *(bf16x8*)&apn[srow * 72 + sch * 8] = pv;
    __syncthreads();
#pragma unroll
    for (int ks = 0; ks < 2; ++ks) {
      bf16x8 b0 = *(const bf16x8*)&apn[l15 * 72 + ks * 32 + g * 8];
      bf16x8 b1 = *(const bf16x8*)&apn[(16 + l15) * 72 + ks * 32 + g * 8];
#pragma unroll
      for (int df = 0; df < 8; ++df) {
        const int d = w * 128 + df * 16 + l15;
        bf16x8 a = *(const bf16x8*)(embnT + (size_t)d * VOC + v0 + ks * 32 + g * 8);
        acc[df][0] = __builtin_amdgcn_mfma_f32_16x16x32_bf16(a, b0, acc[df][0], 0, 0, 0);
        acc[df][1] = __builtin_amdgcn_mfma_f32_16x16x32_bf16(a, b1, acc[df][1], 0, 0, 0);
      }
    }
    __syncthreads();
  }

  // epilogue: D[i=d][j=row] -> kpart[s][row][d], LDS-staged for coalescing
#pragma unroll
  for (int ch = 0; ch < 2; ++ch) {
    if ((w >> 1) == ch) {
#pragma unroll
      for (int df = 0; df < 8; ++df)
#pragma unroll
        for (int rf = 0; rf < 2; ++rf)
#pragma unroll
          for (int j = 0; j < 4; ++j)
            stage[(rf * 16 + l15) * 257 + (w & 1) * 128 + df * 16 + g * 4 + j] =
                acc[df][rf][j];
    }
    __syncthreads();
#pragma unroll
    for (int i = 0; i < 32; ++i) {
      int e = i * 256 + t;
      int r = e >> 8, c = e & 255;
      kpart[((size_t)s * 1024 + rg * 32 + r) * TD + ch * 256 + c] = stage[r * 257 + c];
    }
    __syncthreads();
  }
}

// ---------------------------------------------------------------- K5: kw_out reduce
// grid 2048, block 256.
__global__ __launch_bounds__(256) void k_kwout(const float* __restrict__ kpart,
                                               float* __restrict__ outp) {
  const int idx = blockIdx.x * 256 + threadIdx.x;
  float s = 0.f;
#pragma unroll
  for (int sp = 0; sp < NSPLIT; ++sp) s += kpart[(size_t)sp * 524288 + idx];
  outp[idx] = s;
}

extern "C" void kernel_launch(void* const* d_in, const int* in_sizes, int n_in,
                              void* d_out, int out_size, void* d_ws, size_t ws_size,
                              hipStream_t stream) {
  const float* kw = (const float*)d_in[0];
  const float* Wp = (const float*)d_in[1];
  const float* bp = (const float*)d_in[2];
  const float* We = (const float*)d_in[3];
  float* out = (float*)d_out;
  char* ws = (char*)d_ws;

  unsigned short* kwn = (unsigned short*)(ws);                      // 1,048,576 B
  unsigned short* embn = (unsigned short*)(ws + 1048576);           // 50,593,792 B
  unsigned short* embnT = (unsigned short*)(ws + 51642368);         // 50,593,792 B
  float* normv = (float*)(ws + 102236160);                          // 197,632 B
  float* partial = (float*)(ws + 102433792);                        // 1,581,056 B
  float* rdenom = (float*)(ws + 104014848);                         // 4,096 B
  float* kpart = (float*)(ws + 104018944);                          // 33,554,432 B

  float* kwout = out;
  float* prob = out + 524288;
  float* cosd = out + 51118080;

  hipLaunchKernelGGL(k_proj, dim3(256), dim3(256), 0, stream, kw, Wp, bp, kwn);
  hipLaunchKernelGGL(k_embnorm, dim3(VOC), dim3(64), 0, stream, We, embn, normv);
  hipLaunchKernelGGL(k_transpose, dim3(772, 8), dim3(256), 0, stream, embn, embnT);
  hipLaunchKernelGGL(k_cos, dim3(NCOLG, 8), dim3(256), 0, stream, kwn, embn, cosd, partial);
  hipLaunchKernelGGL(k_denom, dim3(4), dim3(256), 0, stream, partial, rdenom);
  hipLaunchKernelGGL(k_pv, dim3(NSPLIT, 32), dim3(256), 0, stream, cosd, embnT, normv,
                     rdenom, prob, kpart);
  hipLaunchKernelGGL(k_kwout, dim3(2048), dim3(256), 0, stream, kpart, kwout);
}

// Round 2
// 540.518 us; speedup vs baseline: 1.1042x; 1.1042x over previous
//
#include <hip/hip_runtime.h>

#define VOC 49408
#define TD 512
#define DM 768
#define NCOLG 386   // VOC / 128
#define NTILES 772  // VOC / 64
#define NSPLIT 16

typedef __attribute__((ext_vector_type(8))) short bf16x8;
typedef __attribute__((ext_vector_type(4))) float f32x4;

__device__ __forceinline__ unsigned short f2bf(float f) {
  unsigned int u = __float_as_uint(f);
  u += 0x7fffu + ((u >> 16) & 1u);   // RNE
  return (unsigned short)(u >> 16);
}

__device__ __forceinline__ void gload16(const void* g, const void* l) {
  __builtin_amdgcn_global_load_lds(
      (const __attribute__((address_space(1))) void*)g,
      (__attribute__((address_space(3))) void*)l, 16, 0, 0);
}

// ---------------------------------------------------------------- K1: proj + normalize
__global__ __launch_bounds__(256) void k_proj(const float* __restrict__ kw,
                                              const float* __restrict__ Wp,
                                              const float* __restrict__ bp,
                                              unsigned short* __restrict__ kwn) {
  __shared__ float row_lds[4 * DM];
  __shared__ float rsum[4][4];
  __shared__ float rinv_s[4];
  const int t = threadIdx.x;
  const int rb = blockIdx.x * 4;
  for (int i = 0; i < 12; ++i) {
    int idx = i * 256 + t;
    row_lds[idx] = kw[(size_t)rb * DM + idx];
  }
  __syncthreads();
  float acc[4][2] = {};
  for (int m = 0; m < DM; ++m) {
    float w0 = Wp[m * TD + t];
    float w1 = Wp[m * TD + t + 256];
#pragma unroll
    for (int r = 0; r < 4; ++r) {
      float kv = row_lds[r * DM + m];
      acc[r][0] = fmaf(kv, w0, acc[r][0]);
      acc[r][1] = fmaf(kv, w1, acc[r][1]);
    }
  }
  const float b0 = bp[t], b1 = bp[t + 256];
  float p[4];
#pragma unroll
  for (int r = 0; r < 4; ++r) {
    acc[r][0] += b0;
    acc[r][1] += b1;
    p[r] = acc[r][0] * acc[r][0] + acc[r][1] * acc[r][1];
  }
#pragma unroll
  for (int off = 32; off; off >>= 1) {
#pragma unroll
    for (int r = 0; r < 4; ++r) p[r] += __shfl_down(p[r], off);
  }
  const int lane = t & 63, wv = t >> 6;
  if (lane == 0) {
#pragma unroll
    for (int r = 0; r < 4; ++r) rsum[r][wv] = p[r];
  }
  __syncthreads();
  if (t < 4) {
    float s = rsum[t][0] + rsum[t][1] + rsum[t][2] + rsum[t][3];
    rinv_s[t] = 1.0f / fmaxf(sqrtf(s), 1e-8f);
  }
  __syncthreads();
#pragma unroll
  for (int r = 0; r < 4; ++r) {
    float ri = rinv_s[r];
    kwn[(size_t)(rb + r) * TD + t] = f2bf(acc[r][0] * ri);
    kwn[(size_t)(rb + r) * TD + t + 256] = f2bf(acc[r][1] * ri);
  }
}

// ---------------------------------------------------------------- K2: emb normalize (for cos GEMM)
__global__ __launch_bounds__(64) void k_embnorm(const float* __restrict__ We,
                                                unsigned short* __restrict__ embn) {
  const int v = blockIdx.x;
  const int t = threadIdx.x;
  const float* rowp = We + (size_t)v * TD;
  float4 a = *(const float4*)(rowp + t * 8);
  float4 b = *(const float4*)(rowp + t * 8 + 4);
  float ss = a.x * a.x + a.y * a.y + a.z * a.z + a.w * a.w +
             b.x * b.x + b.y * b.y + b.z * b.z + b.w * b.w;
#pragma unroll
  for (int off = 1; off < 64; off <<= 1) ss += __shfl_xor(ss, off);
  const float ri = 1.0f / fmaxf(sqrtf(ss), 1e-8f);
  bf16x8 o;
  o[0] = (short)f2bf(a.x * ri); o[1] = (short)f2bf(a.y * ri);
  o[2] = (short)f2bf(a.z * ri); o[3] = (short)f2bf(a.w * ri);
  o[4] = (short)f2bf(b.x * ri); o[5] = (short)f2bf(b.y * ri);
  o[6] = (short)f2bf(b.z * ri); o[7] = (short)f2bf(b.w * ri);
  *(bf16x8*)(embn + (size_t)v * TD + t * 8) = o;
}

// ---------------------------------------------------------------- K2b: transpose RAW W_emb -> embT bf16 [d][v]
__global__ __launch_bounds__(256) void k_transpose(const float* __restrict__ We,
                                                   unsigned short* __restrict__ embT) {
  __shared__ unsigned short tile[64 * 72];
  const int t = threadIdx.x;
  const int v0 = blockIdx.x * 64, d0 = blockIdx.y * 64;
#pragma unroll
  for (int i = 0; i < 4; ++i) {
    int vl = i * 16 + (t >> 4), c = t & 15;
    float4 f = *(const float4*)(We + (size_t)(v0 + vl) * TD + d0 + c * 4);
    unsigned short* dst = &tile[vl * 72 + c * 4];
    dst[0] = f2bf(f.x); dst[1] = f2bf(f.y); dst[2] = f2bf(f.z); dst[3] = f2bf(f.w);
  }
  __syncthreads();
#pragma unroll
  for (int p = 0; p < 2; ++p) {
    int dl = p * 32 + (t >> 3), vch = t & 7;
    bf16x8 o;
#pragma unroll
    for (int i = 0; i < 8; ++i) o[i] = (short)tile[(vch * 8 + i) * 72 + dl];
    *(bf16x8*)(embT + (size_t)(d0 + dl) * VOC + v0 + vch * 8) = o;
  }
}

// ---------------------------------------------------------------- K3: cos GEMM + sumexp partials
__global__ __launch_bounds__(256) void k_cos(const unsigned short* __restrict__ kwn,
                                             const unsigned short* __restrict__ embn,
                                             float* __restrict__ cosd,
                                             float* __restrict__ partial) {
  __shared__ unsigned short As[128 * 64];
  __shared__ unsigned short Bs[128 * 64];
  __shared__ float rs[2][128];
  const int t = threadIdx.x;
  const int colg = blockIdx.x, rowg = blockIdx.y;
  const int lane = t & 63, w = t >> 6;
  const int wm = w >> 1, wn = w & 1;
  const int g = lane >> 4, l15 = lane & 15;

  f32x4 acc[4][4];
#pragma unroll
  for (int mi = 0; mi < 4; ++mi)
#pragma unroll
    for (int ni = 0; ni < 4; ++ni)
#pragma unroll
      for (int j = 0; j < 4; ++j) acc[mi][ni][j] = 0.0f;

  const unsigned short* Ab = kwn + (size_t)rowg * 128 * TD + (size_t)(t >> 3) * TD + (t & 7) * 8;
  const unsigned short* Bb = embn + (size_t)colg * 128 * TD + (size_t)(t >> 3) * TD + (t & 7) * 8;

  for (int kt = 0; kt < 8; ++kt) {
#pragma unroll
    for (int i = 0; i < 4; ++i) {
      gload16(Ab + (size_t)(i * 32) * TD + kt * 64, (const void*)(As + i * 2048 + w * 512));
      gload16(Bb + (size_t)(i * 32) * TD + kt * 64, (const void*)(Bs + i * 2048 + w * 512));
    }
    __syncthreads();
#pragma unroll
    for (int ks = 0; ks < 2; ++ks) {
      bf16x8 a[4], b[4];
#pragma unroll
      for (int mi = 0; mi < 4; ++mi)
        a[mi] = *(const bf16x8*)&As[(wm * 64 + mi * 16 + l15) * 64 + ks * 32 + g * 8];
#pragma unroll
      for (int ni = 0; ni < 4; ++ni)
        b[ni] = *(const bf16x8*)&Bs[(wn * 64 + ni * 16 + l15) * 64 + ks * 32 + g * 8];
#pragma unroll
      for (int mi = 0; mi < 4; ++mi)
#pragma unroll
        for (int ni = 0; ni < 4; ++ni)
          acc[mi][ni] =
              __builtin_amdgcn_mfma_f32_16x16x32_bf16(a[mi], b[ni], acc[mi][ni], 0, 0, 0);
    }
    __syncthreads();
  }

  const size_t rowbase = (size_t)rowg * 128 + wm * 64;
  const int colbase = colg * 128 + wn * 64;
#pragma unroll
  for (int mi = 0; mi < 4; ++mi) {
    float es[4] = {0.f, 0.f, 0.f, 0.f};
#pragma unroll
    for (int ni = 0; ni < 4; ++ni) {
#pragma unroll
      for (int j = 0; j < 4; ++j) {
        float c = acc[mi][ni][j];
        cosd[(rowbase + mi * 16 + g * 4 + j) * VOC + colbase + ni * 16 + l15] = c;
        es[j] += __expf(c);
      }
    }
#pragma unroll
    for (int j = 0; j < 4; ++j) {
      float e = es[j];
      e += __shfl_xor(e, 1);
      e += __shfl_xor(e, 2);
      e += __shfl_xor(e, 4);
      e += __shfl_xor(e, 8);
      if (l15 == 0) rs[wn][wm * 64 + mi * 16 + g * 4 + j] = e;
    }
  }
  __syncthreads();
  if (t < 128) {
    float srow = rs[0][t] + rs[1][t];
    partial[(size_t)colg * 1024 + rowg * 128 + t] = srow;
  }
}

// ---------------------------------------------------------------- K3b: denom reduce
__global__ __launch_bounds__(256) void k_denom(const float* __restrict__ partial,
                                               float* __restrict__ rdenom) {
  const int row = blockIdx.x * 256 + threadIdx.x;
  float s = 0.f;
  for (int gI = 0; gI < NCOLG; ++gI) s += partial[(size_t)gI * 1024 + row];
  rdenom[row] = 1.0f / s;
}

// ---------------------------------------------------------------- K4: prob + PV GEMM (split-K, LDS-staged)
// grid 512 (XCD-chunked: 16 splits x 32 rowblocks), block 256 = 4 waves.
// Block: 32 rows x 512 d output, ~48 vocab-tiles of 64.
__global__ __launch_bounds__(256, 2) void k_pv(const float* __restrict__ cosd,
                                               const unsigned short* __restrict__ embT,
                                               const float* __restrict__ rdenom,
                                               float* __restrict__ prob,
                                               float* __restrict__ kpart) {
  __shared__ unsigned short Bs[512 * 64];   // 64 KB: [d-row 512][64 v], XOR-swizzled 16B chunks
  __shared__ unsigned short As[32 * 64];    // 4 KB:  [kw-row 32][64 v], XOR-swizzled
  const int t = threadIdx.x;
  const int lane = t & 63, w = t >> 6;
  const int g = lane >> 4, l15 = lane & 15;

  // XCD-chunked block swizzle: same-split blocks (sharing B panel) land on one XCD
  const int h = blockIdx.x;                 // 0..511
  const int L = (h & 7) * 64 + (h >> 3);    // bijective (512 = 8*64)
  const int s = L >> 5;                     // split 0..15
  const int rb = L & 31;                    // rowblock 0..31
  const int t0 = s * 48 + (s < 4 ? s : 4);
  const int t1 = t0 + 48 + (s < 4 ? 1 : 0);

  // A staging constants: thread covers (row = t>>3, 8 v at chunk t&7)
  const int arow = t >> 3;
  const int asl = t & 7;
  const int grow = rb * 32 + arow;
  const float rdv = rdenom[grow];
  const float* cbase = cosd + (size_t)grow * VOC + asl * 8;
  float* pbase = prob + (size_t)grow * VOC + asl * 8;
  const int aoff = arow * 64 + ((asl ^ (arow & 7)) << 3);  // swizzled ushort offset

  // B staging constants: gload i covers rows i*32 + w*8 + (lane>>3), swizzled source chunk
  const int brow_l = lane >> 3;                    // 0..7
  const int bsl = (lane & 7) ^ brow_l;             // pre-swizzled global chunk

  f32x4 acc[2][8];
#pragma unroll
  for (int mi = 0; mi < 2; ++mi)
#pragma unroll
    for (int ni = 0; ni < 8; ++ni)
#pragma unroll
      for (int j = 0; j < 4; ++j) acc[mi][ni][j] = 0.0f;

  // prefetch first cos tile into regs
  float4 c0, c1;
  {
    const float* cp = cbase + (size_t)t0 * 64;
    c0 = *(const float4*)cp;
    c1 = *(const float4*)(cp + 4);
  }

  for (int kt = t0; kt < t1; ++kt) {
    const int v0 = kt * 64;
    __syncthreads();  // all reads of previous tile done -> LDS reusable

    // stage B: 16 x global_load_lds (linear LDS dest, pre-swizzled global src)
#pragma unroll
    for (int i = 0; i < 16; ++i) {
      gload16(embT + (size_t)(i * 32 + w * 8 + brow_l) * VOC + v0 + bsl * 8,
              (const void*)(Bs + i * 2048 + w * 512));
    }

    // compute A: p = exp(cos)*rdenom ; write prob ; pack bf16 to LDS (swizzled)
    float4 p0, p1;
    p0.x = __expf(c0.x) * rdv; p0.y = __expf(c0.y) * rdv;
    p0.z = __expf(c0.z) * rdv; p0.w = __expf(c0.w) * rdv;
    p1.x = __expf(c1.x) * rdv; p1.y = __expf(c1.y) * rdv;
    p1.z = __expf(c1.z) * rdv; p1.w = __expf(c1.w) * rdv;
    *(float4*)(pbase + v0) = p0;
    *(float4*)(pbase + v0 + 4) = p1;
    bf16x8 a8;
    a8[0] = (short)f2bf(p0.x); a8[1] = (short)f2bf(p0.y);
    a8[2] = (short)f2bf(p0.z); a8[3] = (short)f2bf(p0.w);
    a8[4] = (short)f2bf(p1.x); a8[5] = (short)f2bf(p1.y);
    a8[6] = (short)f2bf(p1.z); a8[7] = (short)f2bf(p1.w);
    *(bf16x8*)&As[aoff] = a8;

    // prefetch next cos tile (overlaps with B-stage drain)
    if (kt + 1 < t1) {
      const float* cp = cbase + (size_t)(kt + 1) * 64;
      c0 = *(const float4*)cp;
      c1 = *(const float4*)(cp + 4);
    }

    __syncthreads();  // compiler emits vmcnt(0)+lgkmcnt(0): B + A tiles ready

    // MFMA: wave w owns d-range [w*128, w*128+128)
#pragma unroll
    for (int ks = 0; ks < 2; ++ks) {
      const int ch = (((ks * 4 + g) ^ (l15 & 7)) << 3);
      bf16x8 a0 = *(const bf16x8*)&As[l15 * 64 + ch];
      bf16x8 a1 = *(const bf16x8*)&As[(16 + l15) * 64 + ch];
#pragma unroll
      for (int ni = 0; ni < 8; ++ni) {
        bf16x8 b = *(const bf16x8*)&Bs[(w * 128 + ni * 16 + l15) * 64 + ch];
        acc[0][ni] = __builtin_amdgcn_mfma_f32_16x16x32_bf16(a0, b, acc[0][ni], 0, 0, 0);
        acc[1][ni] = __builtin_amdgcn_mfma_f32_16x16x32_bf16(a1, b, acc[1][ni], 0, 0, 0);
      }
    }
  }

  // epilogue: kpart[s][row][d]
#pragma unroll
  for (int mi = 0; mi < 2; ++mi)
#pragma unroll
    for (int ni = 0; ni < 8; ++ni)
#pragma unroll
      for (int j = 0; j < 4; ++j)
        kpart[((size_t)s * 1024 + rb * 32 + mi * 16 + g * 4 + j) * TD +
              w * 128 + ni * 16 + l15] = acc[mi][ni][j];
}

// ---------------------------------------------------------------- K5: kw_out reduce
__global__ __launch_bounds__(256) void k_kwout(const float* __restrict__ kpart,
                                               float* __restrict__ outp) {
  const int idx = blockIdx.x * 256 + threadIdx.x;
  float s = 0.f;
#pragma unroll
  for (int sp = 0; sp < NSPLIT; ++sp) s += kpart[(size_t)sp * 524288 + idx];
  outp[idx] = s;
}

extern "C" void kernel_launch(void* const* d_in, const int* in_sizes, int n_in,
                              void* d_out, int out_size, void* d_ws, size_t ws_size,
                              hipStream_t stream) {
  const float* kw = (const float*)d_in[0];
  const float* Wp = (const float*)d_in[1];
  const float* bp = (const float*)d_in[2];
  const float* We = (const float*)d_in[3];
  float* out = (float*)d_out;
  char* ws = (char*)d_ws;

  unsigned short* kwn = (unsigned short*)(ws);                      // 1,048,576 B
  unsigned short* embn = (unsigned short*)(ws + 1048576);           // 50,593,792 B
  unsigned short* embT = (unsigned short*)(ws + 51642368);          // 50,593,792 B (raw W_emb^T, bf16)
  float* partial = (float*)(ws + 102236160);                        // 1,581,056 B
  float* rdenom = (float*)(ws + 103817216);                         // 4,096 B
  float* kpart = (float*)(ws + 103821312);                          // 33,554,432 B

  float* kwout = out;
  float* prob = out + 524288;
  float* cosd = out + 51118080;

  hipLaunchKernelGGL(k_proj, dim3(256), dim3(256), 0, stream, kw, Wp, bp, kwn);
  hipLaunchKernelGGL(k_embnorm, dim3(VOC), dim3(64), 0, stream, We, embn);
  hipLaunchKernelGGL(k_transpose, dim3(772, 8), dim3(256), 0, stream, We, embT);
  hipLaunchKernelGGL(k_cos, dim3(NCOLG, 8), dim3(256), 0, stream, kwn, embn, cosd, partial);
  hipLaunchKernelGGL(k_denom, dim3(4), dim3(256), 0, stream, partial, rdenom);
  hipLaunchKernelGGL(k_pv, dim3(512), dim3(256), 0, stream, cosd, embT, rdenom, prob, kpart);
  hipLaunchKernelGGL(k_kwout, dim3(2048), dim3(256), 0, stream, kpart, kwout);
}

// Round 3
// 488.520 us; speedup vs baseline: 1.2217x; 1.1064x over previous
//
#include <hip/hip_runtime.h>

#define VOC 49408
#define TD 512
#define DM 768
#define NCOLG 386   // VOC / 128
#define NTILES 772  // VOC / 64
#define PV_SPLITS 32

typedef __attribute__((ext_vector_type(8))) short bf16x8;
typedef __attribute__((ext_vector_type(4))) short bf16x4;
typedef __attribute__((ext_vector_type(4))) float f32x4;

__device__ __forceinline__ unsigned short f2bf(float f) {
  unsigned int u = __float_as_uint(f);
  u += 0x7fffu + ((u >> 16) & 1u);   // RNE
  return (unsigned short)(u >> 16);
}

__device__ __forceinline__ void gload16(const void* g, const void* l) {
  __builtin_amdgcn_global_load_lds(
      (const __attribute__((address_space(1))) void*)g,
      (__attribute__((address_space(3))) void*)l, 16, 0, 0);
}

// ---------------------------------------------------------------- K1: proj + normalize
__global__ __launch_bounds__(256) void k_proj(const float* __restrict__ kw,
                                              const float* __restrict__ Wp,
                                              const float* __restrict__ bp,
                                              unsigned short* __restrict__ kwn) {
  __shared__ float row_lds[4 * DM];
  __shared__ float rsum[4][4];
  __shared__ float rinv_s[4];
  const int t = threadIdx.x;
  const int rb = blockIdx.x * 4;
  for (int i = 0; i < 12; ++i) {
    int idx = i * 256 + t;
    row_lds[idx] = kw[(size_t)rb * DM + idx];
  }
  __syncthreads();
  float acc[4][2] = {};
  for (int m = 0; m < DM; ++m) {
    float w0 = Wp[m * TD + t];
    float w1 = Wp[m * TD + t + 256];
#pragma unroll
    for (int r = 0; r < 4; ++r) {
      float kv = row_lds[r * DM + m];
      acc[r][0] = fmaf(kv, w0, acc[r][0]);
      acc[r][1] = fmaf(kv, w1, acc[r][1]);
    }
  }
  const float b0 = bp[t], b1 = bp[t + 256];
  float p[4];
#pragma unroll
  for (int r = 0; r < 4; ++r) {
    acc[r][0] += b0;
    acc[r][1] += b1;
    p[r] = acc[r][0] * acc[r][0] + acc[r][1] * acc[r][1];
  }
#pragma unroll
  for (int off = 32; off; off >>= 1) {
#pragma unroll
    for (int r = 0; r < 4; ++r) p[r] += __shfl_down(p[r], off);
  }
  const int lane = t & 63, wv = t >> 6;
  if (lane == 0) {
#pragma unroll
    for (int r = 0; r < 4; ++r) rsum[r][wv] = p[r];
  }
  __syncthreads();
  if (t < 4) {
    float s = rsum[t][0] + rsum[t][1] + rsum[t][2] + rsum[t][3];
    rinv_s[t] = 1.0f / fmaxf(sqrtf(s), 1e-8f);
  }
  __syncthreads();
#pragma unroll
  for (int r = 0; r < 4; ++r) {
    float ri = rinv_s[r];
    kwn[(size_t)(rb + r) * TD + t] = f2bf(acc[r][0] * ri);
    kwn[(size_t)(rb + r) * TD + t + 256] = f2bf(acc[r][1] * ri);
  }
}

// ---------------------------------------------------------------- K2: emb normalize
__global__ __launch_bounds__(64) void k_embnorm(const float* __restrict__ We,
                                                unsigned short* __restrict__ embn) {
  const int v = blockIdx.x;
  const int t = threadIdx.x;
  const float* rowp = We + (size_t)v * TD;
  float4 a = *(const float4*)(rowp + t * 8);
  float4 b = *(const float4*)(rowp + t * 8 + 4);
  float ss = a.x * a.x + a.y * a.y + a.z * a.z + a.w * a.w +
             b.x * b.x + b.y * b.y + b.z * b.z + b.w * b.w;
#pragma unroll
  for (int off = 1; off < 64; off <<= 1) ss += __shfl_xor(ss, off);
  const float ri = 1.0f / fmaxf(sqrtf(ss), 1e-8f);
  bf16x8 o;
  o[0] = (short)f2bf(a.x * ri); o[1] = (short)f2bf(a.y * ri);
  o[2] = (short)f2bf(a.z * ri); o[3] = (short)f2bf(a.w * ri);
  o[4] = (short)f2bf(b.x * ri); o[5] = (short)f2bf(b.y * ri);
  o[6] = (short)f2bf(b.z * ri); o[7] = (short)f2bf(b.w * ri);
  *(bf16x8*)(embn + (size_t)v * TD + t * 8) = o;
}

// ---------------------------------------------------------------- K2b: transpose RAW W_emb -> embT bf16 [d][v]
// grid (8 d-tiles, 772 v-tiles) — d fastest so consecutive blocks share We rows
__global__ __launch_bounds__(256) void k_transpose(const float* __restrict__ We,
                                                   unsigned short* __restrict__ embT) {
  __shared__ unsigned short tile[64 * 72];
  const int t = threadIdx.x;
  const int d0 = blockIdx.x * 64, v0 = blockIdx.y * 64;
#pragma unroll
  for (int i = 0; i < 4; ++i) {
    int vl = i * 16 + (t >> 4), c = t & 15;
    float4 f = *(const float4*)(We + (size_t)(v0 + vl) * TD + d0 + c * 4);
    unsigned short* dst = &tile[vl * 72 + c * 4];
    dst[0] = f2bf(f.x); dst[1] = f2bf(f.y); dst[2] = f2bf(f.z); dst[3] = f2bf(f.w);
  }
  __syncthreads();
#pragma unroll
  for (int p = 0; p < 2; ++p) {
    int dl = p * 32 + (t >> 3), vch = t & 7;
    bf16x8 o;
#pragma unroll
    for (int i = 0; i < 8; ++i) o[i] = (short)tile[(vch * 8 + i) * 72 + dl];
    *(bf16x8*)(embT + (size_t)(d0 + dl) * VOC + v0 + vch * 8) = o;
  }
}

// ---------------------------------------------------------------- K3: cos GEMM + sumexp partials
// grid (8 rowg, 386 colg) — rowg fastest so consecutive blocks share the B tile
__global__ __launch_bounds__(256) void k_cos(const unsigned short* __restrict__ kwn,
                                             const unsigned short* __restrict__ embn,
                                             float* __restrict__ cosd,
                                             float* __restrict__ partial) {
  __shared__ unsigned short As[128 * 64];
  __shared__ unsigned short Bs[128 * 64];
  __shared__ float rs[2][128];
  const int t = threadIdx.x;
  const int rowg = blockIdx.x, colg = blockIdx.y;
  const int lane = t & 63, w = t >> 6;
  const int wm = w >> 1, wn = w & 1;
  const int g = lane >> 4, l15 = lane & 15;

  f32x4 acc[4][4];
#pragma unroll
  for (int mi = 0; mi < 4; ++mi)
#pragma unroll
    for (int ni = 0; ni < 4; ++ni)
#pragma unroll
      for (int j = 0; j < 4; ++j) acc[mi][ni][j] = 0.0f;

  const unsigned short* Ab = kwn + (size_t)rowg * 128 * TD + (size_t)(t >> 3) * TD + (t & 7) * 8;
  const unsigned short* Bb = embn + (size_t)colg * 128 * TD + (size_t)(t >> 3) * TD + (t & 7) * 8;

  for (int kt = 0; kt < 8; ++kt) {
#pragma unroll
    for (int i = 0; i < 4; ++i) {
      gload16(Ab + (size_t)(i * 32) * TD + kt * 64, (const void*)(As + i * 2048 + w * 512));
      gload16(Bb + (size_t)(i * 32) * TD + kt * 64, (const void*)(Bs + i * 2048 + w * 512));
    }
    __syncthreads();
#pragma unroll
    for (int ks = 0; ks < 2; ++ks) {
      bf16x8 a[4], b[4];
#pragma unroll
      for (int mi = 0; mi < 4; ++mi)
        a[mi] = *(const bf16x8*)&As[(wm * 64 + mi * 16 + l15) * 64 + ks * 32 + g * 8];
#pragma unroll
      for (int ni = 0; ni < 4; ++ni)
        b[ni] = *(const bf16x8*)&Bs[(wn * 64 + ni * 16 + l15) * 64 + ks * 32 + g * 8];
#pragma unroll
      for (int mi = 0; mi < 4; ++mi)
#pragma unroll
        for (int ni = 0; ni < 4; ++ni)
          acc[mi][ni] =
              __builtin_amdgcn_mfma_f32_16x16x32_bf16(a[mi], b[ni], acc[mi][ni], 0, 0, 0);
    }
    __syncthreads();
  }

  const size_t rowbase = (size_t)rowg * 128 + wm * 64;
  const int colbase = colg * 128 + wn * 64;
#pragma unroll
  for (int mi = 0; mi < 4; ++mi) {
    float es[4] = {0.f, 0.f, 0.f, 0.f};
#pragma unroll
    for (int ni = 0; ni < 4; ++ni) {
#pragma unroll
      for (int j = 0; j < 4; ++j) {
        float c = acc[mi][ni][j];
        cosd[(rowbase + mi * 16 + g * 4 + j) * VOC + colbase + ni * 16 + l15] = c;
        es[j] += __expf(c);
      }
    }
#pragma unroll
    for (int j = 0; j < 4; ++j) {
      float e = es[j];
      e += __shfl_xor(e, 1);
      e += __shfl_xor(e, 2);
      e += __shfl_xor(e, 4);
      e += __shfl_xor(e, 8);
      if (l15 == 0) rs[wn][wm * 64 + mi * 16 + g * 4 + j] = e;
    }
  }
  __syncthreads();
  if (t < 128) {
    float srow = rs[0][t] + rs[1][t];
    partial[(size_t)colg * 1024 + rowg * 128 + t] = srow;
  }
}

// ---------------------------------------------------------------- K3b: denom reduce
__global__ __launch_bounds__(256) void k_denom(const float* __restrict__ partial,
                                               float* __restrict__ rdenom) {
  const int row = blockIdx.x * 256 + threadIdx.x;
  float s = 0.f;
  for (int gI = 0; gI < NCOLG; ++gI) s += partial[(size_t)gI * 1024 + row];
  rdenom[row] = 1.0f / s;
}

// ---------------------------------------------------------------- K4: prob + PV GEMM
// BM=128, BN=256, BK=64. grid (8 rowg, 2 colg, 32 splits) = 512 blocks, 4 waves.
// colg==0 blocks also write prob. A = bf16(exp(cos)*rdv) staged via LDS (swizzled),
// B = embT staged via global_load_lds with pre-swizzled source.
__global__ __launch_bounds__(256, 2) void k_pv(const float* __restrict__ cosd,
                                               const unsigned short* __restrict__ embT,
                                               const float* __restrict__ rdenom,
                                               float* __restrict__ prob,
                                               float* __restrict__ kpart) {
  __shared__ unsigned short As[128 * 64];   // 16 KB, LDS[r][c]=G[r][c^(r&7)]
  __shared__ unsigned short Bs[256 * 64];   // 32 KB, same swizzle
  const int t = threadIdx.x;
  const int lane = t & 63, w = t >> 6;        // 4 waves
  const int wr = w >> 1, wc = w & 1;          // 2x2 wave grid (64x128 per wave)
  const int g = lane >> 4, l15 = lane & 15;
  const int rowg = blockIdx.x;                // 0..7
  const int colg = blockIdx.y;                // 0..1
  const int s = blockIdx.z;                   // 0..31
  const int t0 = s * 24 + (s < 4 ? s : 4);
  const int t1 = t0 + 24 + (s < 4 ? 1 : 0);

  // A staging: thread -> row ar = t>>1, interleave half ah = t&1 (float4s 2i+ah)
  const int ar = t >> 1, ah = t & 1;
  const int grow = rowg * 128 + ar;
  const float rdv = rdenom[grow];
  const float* cbase = cosd + (size_t)grow * VOC + ah * 4;
  float* pbase = prob + (size_t)grow * VOC + ah * 4;

  // B staging: gload i stages rows colg*256 + i*32 + w*8 + (lane>>3)
  const int brow_l = lane >> 3;
  const int bsl = (lane & 7) ^ brow_l;        // pre-swizzled source chunk

  f32x4 acc[4][8];
#pragma unroll
  for (int mi = 0; mi < 4; ++mi)
#pragma unroll
    for (int ni = 0; ni < 8; ++ni)
#pragma unroll
      for (int j = 0; j < 4; ++j) acc[mi][ni][j] = 0.0f;

  // prefetch first cos tile: float4 index j = 2i+ah -> v = 8i + 4ah
  float4 cc[8];
  {
    const float* cp = cbase + (size_t)t0 * 64;
#pragma unroll
    for (int i = 0; i < 8; ++i) cc[i] = *(const float4*)(cp + i * 8);
  }

  for (int kt = t0; kt < t1; ++kt) {
    const int v0 = kt * 64;
    __syncthreads();  // previous MFMA reads done -> LDS reusable

    // stage B: 8 x global_load_lds (linear LDS dest, pre-swizzled global src)
#pragma unroll
    for (int i = 0; i < 8; ++i) {
      gload16(embT + (size_t)(colg * 256 + i * 32 + w * 8 + brow_l) * VOC + v0 + bsl * 8,
              (const void*)(Bs + (i * 32 + w * 8) * 64));
    }

    // A: p = exp(cos)*rdv from prefetched regs; write prob (colg 0); pack to LDS
    float4 px[8];
#pragma unroll
    for (int i = 0; i < 8; ++i) {
      px[i].x = __expf(cc[i].x) * rdv;
      px[i].y = __expf(cc[i].y) * rdv;
      px[i].z = __expf(cc[i].z) * rdv;
      px[i].w = __expf(cc[i].w) * rdv;
    }
    if (colg == 0) {
#pragma unroll
      for (int i = 0; i < 8; ++i) *(float4*)(pbase + v0 + i * 8) = px[i];
    }
#pragma unroll
    for (int i = 0; i < 8; ++i) {
      bf16x4 b4;
      b4[0] = (short)f2bf(px[i].x);
      b4[1] = (short)f2bf(px[i].y);
      b4[2] = (short)f2bf(px[i].z);
      b4[3] = (short)f2bf(px[i].w);
      // float4 j=2i+ah -> chunk i, sub ah; swizzled slot i^(ar&7)
      *(bf16x4*)&As[ar * 64 + ((i ^ (ar & 7)) << 3) + ah * 4] = b4;
    }

    // prefetch next cos tile (completes at the barrier's vmcnt drain)
    if (kt + 1 < t1) {
      const float* cp = cbase + (size_t)(kt + 1) * 64;
#pragma unroll
      for (int i = 0; i < 8; ++i) cc[i] = *(const float4*)(cp + i * 8);
    }

    __syncthreads();  // B gloads + A ds_writes complete

    // MFMA: wave (wr,wc) owns rows [wr*64,+64) x d [wc*128,+128)
#pragma unroll
    for (int ks = 0; ks < 2; ++ks) {
      const int ch = (((ks * 4 + g) ^ (l15 & 7)) << 3);
      bf16x8 a[4];
#pragma unroll
      for (int mi = 0; mi < 4; ++mi)
        a[mi] = *(const bf16x8*)&As[(wr * 64 + mi * 16 + l15) * 64 + ch];
#pragma unroll
      for (int ni = 0; ni < 8; ++ni) {
        bf16x8 b = *(const bf16x8*)&Bs[(wc * 128 + ni * 16 + l15) * 64 + ch];
#pragma unroll
        for (int mi = 0; mi < 4; ++mi)
          acc[mi][ni] = __builtin_amdgcn_mfma_f32_16x16x32_bf16(a[mi], b, acc[mi][ni], 0, 0, 0);
      }
    }
  }

  // epilogue: kpart[s][row][d]
#pragma unroll
  for (int mi = 0; mi < 4; ++mi)
#pragma unroll
    for (int ni = 0; ni < 8; ++ni)
#pragma unroll
      for (int j = 0; j < 4; ++j)
        kpart[((size_t)s * 1024 + rowg * 128 + wr * 64 + mi * 16 + g * 4 + j) * TD +
              colg * 256 + wc * 128 + ni * 16 + l15] = acc[mi][ni][j];
}

// ---------------------------------------------------------------- K5: kw_out reduce
__global__ __launch_bounds__(256) void k_kwout(const float* __restrict__ kpart,
                                               float* __restrict__ outp) {
  const int idx = blockIdx.x * 256 + threadIdx.x;
  float s = 0.f;
#pragma unroll
  for (int sp = 0; sp < PV_SPLITS; ++sp) s += kpart[(size_t)sp * 524288 + idx];
  outp[idx] = s;
}

extern "C" void kernel_launch(void* const* d_in, const int* in_sizes, int n_in,
                              void* d_out, int out_size, void* d_ws, size_t ws_size,
                              hipStream_t stream) {
  const float* kw = (const float*)d_in[0];
  const float* Wp = (const float*)d_in[1];
  const float* bp = (const float*)d_in[2];
  const float* We = (const float*)d_in[3];
  float* out = (float*)d_out;
  char* ws = (char*)d_ws;

  // ws layout (peak 117.7 MB; kpart aliases dead kwn/embn/partial):
  unsigned short* embT = (unsigned short*)ws;                       // 50,593,792 B
  char* r1 = ws + 50593792;
  unsigned short* kwn = (unsigned short*)(r1);                      // 1,048,576 B
  unsigned short* embn = (unsigned short*)(r1 + 1048576);           // 50,593,792 B
  float* partial = (float*)(r1 + 51642368);                         // 1,581,056 B
  float* kpart = (float*)(r1);                                      // 67,108,864 B (alias)
  float* rdenom = (float*)(ws + 50593792 + 67108864);               // 4,096 B

  float* kwout = out;
  float* prob = out + 524288;
  float* cosd = out + 51118080;

  hipLaunchKernelGGL(k_proj, dim3(256), dim3(256), 0, stream, kw, Wp, bp, kwn);
  hipLaunchKernelGGL(k_embnorm, dim3(VOC), dim3(64), 0, stream, We, embn);
  hipLaunchKernelGGL(k_transpose, dim3(8, 772), dim3(256), 0, stream, We, embT);
  hipLaunchKernelGGL(k_cos, dim3(8, NCOLG), dim3(256), 0, stream, kwn, embn, cosd, partial);
  hipLaunchKernelGGL(k_denom, dim3(4), dim3(256), 0, stream, partial, rdenom);
  hipLaunchKernelGGL(k_pv, dim3(8, 2, PV_SPLITS), dim3(256), 0, stream, cosd, embT, rdenom,
                     prob, kpart);
  hipLaunchKernelGGL(k_kwout, dim3(2048), dim3(256), 0, stream, kpart, kwout);
}